// Round 2
// baseline (6752.705 us; speedup 1.0000x reference)
//
#include <hip/hip_runtime.h>
#include <math.h>

#define NB 16
#define NLOC 21824
#define NCLS 80
#define NLVL 5
#define MM 5000
#define CAP 4096
#define EPB 1745920  // entries per batch = NLOC*NCLS

// level entry starts (within batch, units of entries = loc*80+cls)
__device__ __forceinline__ int level_of(int r) {
    return (r < 1310720) ? 0 : (r < 1638400) ? 1 : (r < 1720320) ? 2 : (r < 1740800) ? 3 : 4;
}
__device__ __constant__ int d_estart[5] = {0, 1310720, 1638400, 1720320, 1740800};
__device__ __constant__ int d_lstart[5] = {0, 16384, 20480, 21504, 21760};

// ---------------- Kernel A: per-(b,l) 15-bit histogram of candidate valbits ----------------
__global__ void k_hist(const float* __restrict__ cls, const float* __restrict__ ctr,
                       unsigned int* __restrict__ hist) {
    const long long total = (long long)NB * EPB;
    for (long long e = (long long)blockIdx.x * blockDim.x + threadIdx.x; e < total;
         e += (long long)gridDim.x * blockDim.x) {
        float x = cls[e];
        if (x <= -2.945f) continue;  // sigmoid(-2.945)=0.049968 < 0.05f, safe prescreen
        double sd = 1.0 / (1.0 + exp(-(double)x));
        float sf = (float)sd;
        if (!(sf > 0.05f)) continue;
        int b = (int)(e / EPB);
        int r = (int)(e - (long long)b * EPB);
        int l = level_of(r);
        int locg = r / 80;
        float c = ctr[(long long)b * NLOC + locg];
        double cd = 1.0 / (1.0 + exp(-(double)c));
        float val = sf * (float)cd;
        unsigned int vb = __float_as_uint(val);
        atomicAdd(&hist[(((long long)b * 5 + l) << 15) + (vb >> 15)], 1u);
    }
}

// ---------------- Kernel B: find cutoff bucket per (b,l) ----------------
__global__ void k_cutoff(const unsigned int* __restrict__ hist, unsigned int* __restrict__ bcut) {
    int g = blockIdx.x;  // 0..79
    const unsigned int* h = hist + ((long long)g << 15);
    __shared__ unsigned int ssum[256];
    int t = threadIdx.x;  // 256 threads, 128 buckets each
    unsigned int s = 0;
    for (int i = 0; i < 128; i++) s += h[t * 128 + i];
    ssum[t] = s;
    __syncthreads();
    if (t == 0) {
        unsigned int cum = 0;
        int bucket = 0;
        int ch = 255;
        for (; ch >= 0; ch--) {
            if (cum + ssum[ch] >= 1000u) break;
            cum += ssum[ch];
        }
        if (ch >= 0) {
            int bi = ch * 128 + 127;
            for (; bi > ch * 128; bi--) {
                unsigned int c = h[bi];
                if (cum + c >= 1000u) break;
                cum += c;
            }
            bucket = bi;
        }
        bcut[g] = (unsigned int)bucket;
    }
}

// ---------------- Kernel C: compact candidates >= cutoff bucket ----------------
__global__ void k_compact(const float* __restrict__ cls, const float* __restrict__ ctr,
                          const unsigned int* __restrict__ bcut, unsigned int* __restrict__ cnt,
                          unsigned long long* __restrict__ compact) {
    const long long total = (long long)NB * EPB;
    for (long long e = (long long)blockIdx.x * blockDim.x + threadIdx.x; e < total;
         e += (long long)gridDim.x * blockDim.x) {
        float x = cls[e];
        if (x <= -2.945f) continue;
        double sd = 1.0 / (1.0 + exp(-(double)x));
        float sf = (float)sd;
        if (!(sf > 0.05f)) continue;
        int b = (int)(e / EPB);
        int r = (int)(e - (long long)b * EPB);
        int l = level_of(r);
        int locg = r / 80;
        float c = ctr[(long long)b * NLOC + locg];
        double cd = 1.0 / (1.0 + exp(-(double)c));
        float val = sf * (float)cd;
        unsigned int vb = __float_as_uint(val);
        int g = b * 5 + l;
        if ((vb >> 15) >= bcut[g]) {
            unsigned int pos = atomicAdd(&cnt[g], 1u);
            if (pos < CAP) {
                unsigned int idx = (unsigned int)(r - d_estart[l]);
                compact[(long long)g * CAP + pos] =
                    ((unsigned long long)vb << 21) | (unsigned long long)(0x1FFFFFu - idx);
            }
        }
    }
}

// ---------------- Kernel D: per-(b,l) bitonic sort + build global keys ----------------
__global__ void k_select(const unsigned int* __restrict__ cnt,
                         const unsigned long long* __restrict__ compact,
                         unsigned long long* __restrict__ pool) {
    __shared__ unsigned long long sk[CAP];
    int g = blockIdx.x;
    int b = g / 5, l = g % 5;
    int count = min((int)cnt[g], CAP);
    for (int p = threadIdx.x; p < CAP; p += blockDim.x)
        sk[p] = (p < count) ? compact[(long long)g * CAP + p] : 0ULL;
    __syncthreads();
    for (int k = 2; k <= CAP; k <<= 1) {
        for (int j = k >> 1; j > 0; j >>= 1) {
            for (int i = threadIdx.x; i < CAP; i += blockDim.x) {
                int ixj = i ^ j;
                if (ixj > i) {
                    unsigned long long a = sk[i], bb = sk[ixj];
                    bool desc = ((i & k) == 0);
                    if (desc ? (a < bb) : (a > bb)) { sk[i] = bb; sk[ixj] = a; }
                }
            }
            __syncthreads();
        }
    }
    int ksel = min(1000, count);
    for (int r = threadIdx.x; r < 1000; r += blockDim.x) {
        unsigned long long gk = 0ULL;
        if (r < ksel) {
            unsigned long long key = sk[r];
            unsigned int vb = (unsigned int)(key >> 21);
            unsigned int idx = 0x1FFFFFu - (unsigned int)(key & 0x1FFFFFu);
            float val = __uint_as_float(vb);
            float sc = sqrtf(val);
            unsigned long long sb = (unsigned long long)__float_as_uint(sc);
            gk = (sb << 34) | ((unsigned long long)(7 - l) << 31) |
                 ((unsigned long long)(1023 - r) << 21) | (unsigned long long)idx;
        }
        pool[(long long)b * MM + l * 1000 + r] = gk;
    }
}

// ---------------- Kernel E: per-batch global bitonic sort (8192) ----------------
__global__ void k_gsort(const unsigned long long* __restrict__ pool,
                        unsigned long long* __restrict__ sorted) {
    __shared__ unsigned long long sk[8192];
    int b = blockIdx.x;
    for (int p = threadIdx.x; p < 8192; p += blockDim.x)
        sk[p] = (p < MM) ? pool[(long long)b * MM + p] : 0ULL;
    __syncthreads();
    for (int k = 2; k <= 8192; k <<= 1) {
        for (int j = k >> 1; j > 0; j >>= 1) {
            for (int i = threadIdx.x; i < 8192; i += blockDim.x) {
                int ixj = i ^ j;
                if (ixj > i) {
                    unsigned long long a = sk[i], bb = sk[ixj];
                    bool desc = ((i & k) == 0);
                    if (desc ? (a < bb) : (a > bb)) { sk[i] = bb; sk[ixj] = a; }
                }
            }
            __syncthreads();
        }
    }
    for (int p = threadIdx.x; p < MM; p += blockDim.x)
        sorted[(long long)b * MM + p] = sk[p];
}

// ---------------- Kernel F: decode boxes/scores/classes ----------------
__global__ void k_decode(const unsigned long long* __restrict__ sorted,
                         const float* __restrict__ reg, const float* __restrict__ locs,
                         float4* __restrict__ boxesWS, float* __restrict__ scoresWS,
                         float* __restrict__ clsWS, unsigned int* __restrict__ validWS) {
    int g = blockIdx.x * blockDim.x + threadIdx.x;
    if (g >= NB * MM) return;
    int b = g / MM;
    unsigned long long gk = sorted[g];
    float4 bx = make_float4(0.f, 0.f, 0.f, 0.f);
    float sc = 0.f, cf = 0.f;
    unsigned int v = 0;
    if (gk) {
        sc = __uint_as_float((unsigned int)(gk >> 34));
        int l = 7 - (int)((gk >> 31) & 7);
        int idx = (int)(gk & 0x1FFFFF);
        int loc = idx / 80;
        int c = idx - loc * 80;
        int gl = d_lstart[l] + loc;
        float lx = locs[gl * 2], ly = locs[gl * 2 + 1];
        const float* r4 = reg + ((long long)b * NLOC + gl) * 4;
        float x1 = fminf(fmaxf(lx - r4[0], 0.f), 1024.f);
        float y1 = fminf(fmaxf(ly - r4[1], 0.f), 1024.f);
        float x2 = fminf(fmaxf(lx + r4[2], 0.f), 1024.f);
        float y2 = fminf(fmaxf(ly + r4[3], 0.f), 1024.f);
        bx = make_float4(x1, y1, x2, y2);
        cf = (float)(c + 1);
        v = 1;
    }
    boxesWS[g] = bx;
    scoresWS[g] = sc;
    clsWS[g] = cf;
    validWS[g] = v;
}

// ---------------- Kernel G: sequential NMS + post-select + output ----------------
__global__ __launch_bounds__(1024) void k_nms(const float4* __restrict__ boxesWS,
                                              const float* __restrict__ scoresWS,
                                              const float* __restrict__ clsWS,
                                              const unsigned int* __restrict__ validWS,
                                              float* __restrict__ out) {
    int b = blockIdx.x;
    int t = threadIdx.x;
    __shared__ unsigned char kf[MM];
    __shared__ int s_min;
    __shared__ int s_cnt;
    float4 bx[5];
    float ar[5];
    int base = b * MM;
    for (int c = 0; c < 5; c++) {
        int p = t + 1024 * c;
        bx[c] = make_float4(0.f, 0.f, 0.f, 0.f);
        ar[c] = 0.f;
        if (p < MM) {
            kf[p] = (unsigned char)validWS[base + p];
            float4 v = boxesWS[base + p];
            bx[c] = v;
            ar[c] = (v.z - v.x) * (v.w - v.y);
        }
    }
    __syncthreads();
    int i = -1;
    while (true) {
        int nh = -1;
        int wstart = i + 1;
        while (wstart < MM) {
            if (t == 0) s_min = 0x7FFFFFFF;
            __syncthreads();
            int p = wstart + t;
            if (p < MM && kf[p]) atomicMin(&s_min, p);
            __syncthreads();
            int sm = s_min;
            __syncthreads();
            if (sm != 0x7FFFFFFF) { nh = sm; break; }
            wstart += 1024;
        }
        if (nh < 0) break;
        i = nh;
        float4 hb = boxesWS[base + i];  // broadcast load
        float ha = (hb.z - hb.x) * (hb.w - hb.y);
        for (int c = 0; c < 5; c++) {
            int p = t + 1024 * c;
            if (p > i && p < MM && kf[p]) {
                float xi1 = fmaxf(hb.x, bx[c].x);
                float yi1 = fmaxf(hb.y, bx[c].y);
                float xi2 = fminf(hb.z, bx[c].z);
                float yi2 = fminf(hb.w, bx[c].w);
                float inter = fmaxf(xi2 - xi1, 0.f) * fmaxf(yi2 - yi1, 0.f);
                float iou = inter / fmaxf(ha + ar[c] - inter, 1e-9f);
                if (iou > 0.6f) kf[p] = 0;
            }
        }
        __syncthreads();
    }
    // n_det
    if (t == 0) s_cnt = 0;
    __syncthreads();
    int lc = 0;
    for (int c = 0; c < 5; c++) {
        int p = t + 1024 * c;
        if (p < MM && kf[p]) lc++;
    }
    if (lc) atomicAdd(&s_cnt, lc);
    __syncthreads();
    int n_det = s_cnt;
    float thresh = -INFINITY;
    if (n_det > 100) {
        int lo = 0, hi = MM - 1;
        while (lo < hi) {
            int mid = (lo + hi) >> 1;
            __syncthreads();
            if (t == 0) s_cnt = 0;
            __syncthreads();
            int c2 = 0;
            for (int c = 0; c < 5; c++) {
                int p = t + 1024 * c;
                if (p < MM && p <= mid && kf[p]) c2++;
            }
            if (c2) atomicAdd(&s_cnt, c2);
            __syncthreads();
            if (s_cnt >= 100) hi = mid; else lo = mid + 1;
            __syncthreads();
        }
        thresh = scoresWS[base + lo];
    }
    // outputs: [boxes | scores | classes | keep]
    float* ob = out;
    float* os = out + NB * MM * 4;
    float* oc = out + NB * MM * 5;
    float* ok = out + NB * MM * 6;
    for (int c = 0; c < 5; c++) {
        int p = t + 1024 * c;
        if (p < MM) {
            int g = base + p;
            float s = scoresWS[g];
            bool k = kf[p] && (s >= thresh) && (s >= 0.05f);
            float km = k ? 1.0f : 0.0f;
            float4 v = bx[c];
            ((float4*)ob)[g] = make_float4(v.x * km, v.y * km, v.z * km, v.w * km);
            os[g] = s * km;
            oc[g] = clsWS[g] * km;
            ok[g] = km;
        }
    }
}

extern "C" void kernel_launch(void* const* d_in, const int* in_sizes, int n_in,
                              void* d_out, int out_size, void* d_ws, size_t ws_size,
                              hipStream_t stream) {
    const float* cls = (const float*)d_in[0];
    const float* reg = (const float*)d_in[1];
    const float* ctr = (const float*)d_in[2];
    const float* locs = (const float*)d_in[3];
    (void)in_sizes; (void)n_in; (void)out_size; (void)ws_size;

    char* ws = (char*)d_ws;
    unsigned int* hist = (unsigned int*)(ws);                      // 80*32768*4 = 10,485,760
    unsigned int* cnt = (unsigned int*)(ws + 10485760);            // 320
    unsigned int* bcut = (unsigned int*)(ws + 10486080);           // 320
    unsigned long long* compact = (unsigned long long*)(ws + 10486400);  // 80*4096*8 = 2,621,440
    unsigned long long* pool = (unsigned long long*)(ws + 13107840);     // 16*5000*8 = 640,000
    unsigned long long* sorted = (unsigned long long*)(ws + 13747840);   // 640,000
    float4* boxesWS = (float4*)(ws + 14387840);                    // 16*5000*16 = 1,280,000
    float* scoresWS = (float*)(ws + 15667840);                     // 320,000
    float* clsWS = (float*)(ws + 15987840);                        // 320,000
    unsigned int* validWS = (unsigned int*)(ws + 16307840);        // 320,000

    hipMemsetAsync(ws, 0, 10486080, stream);  // hist + cnt
    hipLaunchKernelGGL(k_hist, dim3(4096), dim3(256), 0, stream, cls, ctr, hist);
    hipLaunchKernelGGL(k_cutoff, dim3(80), dim3(256), 0, stream, hist, bcut);
    hipLaunchKernelGGL(k_compact, dim3(4096), dim3(256), 0, stream, cls, ctr, bcut, cnt, compact);
    hipLaunchKernelGGL(k_select, dim3(80), dim3(1024), 0, stream, cnt, compact, pool);
    hipLaunchKernelGGL(k_gsort, dim3(16), dim3(1024), 0, stream, pool, sorted);
    hipLaunchKernelGGL(k_decode, dim3((NB * MM + 255) / 256), dim3(256), 0, stream,
                       sorted, reg, locs, boxesWS, scoresWS, clsWS, validWS);
    hipLaunchKernelGGL(k_nms, dim3(16), dim3(1024), 0, stream,
                       boxesWS, scoresWS, clsWS, validWS, (float*)d_out);
}

// Round 3
// 2487.951 us; speedup vs baseline: 2.7142x; 2.7142x over previous
//
#include <hip/hip_runtime.h>
#include <math.h>

#define NB 16
#define NLOC 21824
#define NCLS 80
#define NLVL 5
#define MM 5000
#define MROWS 5024      // MM padded to 16*... for scan groups (314 groups of 16)
#define CAP 4096
#define EPB 1745920     // entries per batch = NLOC*NCLS

__device__ __forceinline__ int level_of(int r) {
    return (r < 1310720) ? 0 : (r < 1638400) ? 1 : (r < 1720320) ? 2 : (r < 1740800) ? 3 : 4;
}
__device__ __constant__ int d_estart[5] = {0, 1310720, 1638400, 1720320, 1740800};
__device__ __constant__ int d_lstart[5] = {0, 16384, 20480, 21504, 21760};

// ---------------- Kernel A: per-(b,l) 15-bit histogram of candidate valbits ----------------
__global__ void k_hist(const float* __restrict__ cls, const float* __restrict__ ctr,
                       unsigned int* __restrict__ hist) {
    const long long total = (long long)NB * EPB;
    for (long long e = (long long)blockIdx.x * blockDim.x + threadIdx.x; e < total;
         e += (long long)gridDim.x * blockDim.x) {
        float x = cls[e];
        if (x <= -2.945f) continue;  // sigmoid(-2.945)=0.049968 < 0.05f, safe prescreen
        double sd = 1.0 / (1.0 + exp(-(double)x));
        float sf = (float)sd;
        if (!(sf > 0.05f)) continue;
        int b = (int)(e / EPB);
        int r = (int)(e - (long long)b * EPB);
        int l = level_of(r);
        int locg = r / 80;
        float c = ctr[(long long)b * NLOC + locg];
        double cd = 1.0 / (1.0 + exp(-(double)c));
        float val = sf * (float)cd;
        unsigned int vb = __float_as_uint(val);
        atomicAdd(&hist[(((long long)b * 5 + l) << 15) + (vb >> 15)], 1u);
    }
}

// ---------------- Kernel B: find cutoff bucket per (b,l) ----------------
__global__ void k_cutoff(const unsigned int* __restrict__ hist, unsigned int* __restrict__ bcut) {
    int g = blockIdx.x;  // 0..79
    const unsigned int* h = hist + ((long long)g << 15);
    __shared__ unsigned int ssum[256];
    int t = threadIdx.x;
    unsigned int s = 0;
    for (int i = 0; i < 128; i++) s += h[t * 128 + i];
    ssum[t] = s;
    __syncthreads();
    if (t == 0) {
        unsigned int cum = 0;
        int bucket = 0;
        int ch = 255;
        for (; ch >= 0; ch--) {
            if (cum + ssum[ch] >= 1000u) break;
            cum += ssum[ch];
        }
        if (ch >= 0) {
            int bi = ch * 128 + 127;
            for (; bi > ch * 128; bi--) {
                unsigned int c = h[bi];
                if (cum + c >= 1000u) break;
                cum += c;
            }
            bucket = bi;
        }
        bcut[g] = (unsigned int)bucket;
    }
}

// ---------------- Kernel C: compact candidates >= cutoff bucket ----------------
__global__ void k_compact(const float* __restrict__ cls, const float* __restrict__ ctr,
                          const unsigned int* __restrict__ bcut, unsigned int* __restrict__ cnt,
                          unsigned long long* __restrict__ compact) {
    const long long total = (long long)NB * EPB;
    for (long long e = (long long)blockIdx.x * blockDim.x + threadIdx.x; e < total;
         e += (long long)gridDim.x * blockDim.x) {
        float x = cls[e];
        if (x <= -2.945f) continue;
        double sd = 1.0 / (1.0 + exp(-(double)x));
        float sf = (float)sd;
        if (!(sf > 0.05f)) continue;
        int b = (int)(e / EPB);
        int r = (int)(e - (long long)b * EPB);
        int l = level_of(r);
        int locg = r / 80;
        float c = ctr[(long long)b * NLOC + locg];
        double cd = 1.0 / (1.0 + exp(-(double)c));
        float val = sf * (float)cd;
        unsigned int vb = __float_as_uint(val);
        int g = b * 5 + l;
        if ((vb >> 15) >= bcut[g]) {
            unsigned int pos = atomicAdd(&cnt[g], 1u);
            if (pos < CAP) {
                unsigned int idx = (unsigned int)(r - d_estart[l]);
                compact[(long long)g * CAP + pos] =
                    ((unsigned long long)vb << 21) | (unsigned long long)(0x1FFFFFu - idx);
            }
        }
    }
}

// ---------------- Kernel D: per-(b,l) bitonic sort + build global keys ----------------
__global__ void k_select(const unsigned int* __restrict__ cnt,
                         const unsigned long long* __restrict__ compact,
                         unsigned long long* __restrict__ pool) {
    __shared__ unsigned long long sk[CAP];
    int g = blockIdx.x;
    int b = g / 5, l = g % 5;
    int count = min((int)cnt[g], CAP);
    for (int p = threadIdx.x; p < CAP; p += blockDim.x)
        sk[p] = (p < count) ? compact[(long long)g * CAP + p] : 0ULL;
    __syncthreads();
    for (int k = 2; k <= CAP; k <<= 1) {
        for (int j = k >> 1; j > 0; j >>= 1) {
            for (int i = threadIdx.x; i < CAP; i += blockDim.x) {
                int ixj = i ^ j;
                if (ixj > i) {
                    unsigned long long a = sk[i], bb = sk[ixj];
                    bool desc = ((i & k) == 0);
                    if (desc ? (a < bb) : (a > bb)) { sk[i] = bb; sk[ixj] = a; }
                }
            }
            __syncthreads();
        }
    }
    int ksel = min(1000, count);
    for (int r = threadIdx.x; r < 1000; r += blockDim.x) {
        unsigned long long gk = 0ULL;
        if (r < ksel) {
            unsigned long long key = sk[r];
            unsigned int vb = (unsigned int)(key >> 21);
            unsigned int idx = 0x1FFFFFu - (unsigned int)(key & 0x1FFFFFu);
            float val = __uint_as_float(vb);
            float sc = sqrtf(val);
            unsigned long long sb = (unsigned long long)__float_as_uint(sc);
            gk = (sb << 34) | ((unsigned long long)(7 - l) << 31) |
                 ((unsigned long long)(1023 - r) << 21) | (unsigned long long)idx;
        }
        pool[(long long)b * MM + l * 1000 + r] = gk;
    }
}

// ---------------- Kernel E: per-batch global bitonic sort (8192) ----------------
__global__ void k_gsort(const unsigned long long* __restrict__ pool,
                        unsigned long long* __restrict__ sorted) {
    __shared__ unsigned long long sk[8192];
    int b = blockIdx.x;
    for (int p = threadIdx.x; p < 8192; p += blockDim.x)
        sk[p] = (p < MM) ? pool[(long long)b * MM + p] : 0ULL;
    __syncthreads();
    for (int k = 2; k <= 8192; k <<= 1) {
        for (int j = k >> 1; j > 0; j >>= 1) {
            for (int i = threadIdx.x; i < 8192; i += blockDim.x) {
                int ixj = i ^ j;
                if (ixj > i) {
                    unsigned long long a = sk[i], bb = sk[ixj];
                    bool desc = ((i & k) == 0);
                    if (desc ? (a < bb) : (a > bb)) { sk[i] = bb; sk[ixj] = a; }
                }
            }
            __syncthreads();
        }
    }
    for (int p = threadIdx.x; p < MM; p += blockDim.x)
        sorted[(long long)b * MM + p] = sk[p];
}

// ---------------- Kernel F: decode boxes/scores/classes ----------------
__global__ void k_decode(const unsigned long long* __restrict__ sorted,
                         const float* __restrict__ reg, const float* __restrict__ locs,
                         float4* __restrict__ boxesWS, float* __restrict__ scoresWS,
                         float* __restrict__ clsWS, unsigned int* __restrict__ validWS) {
    int g = blockIdx.x * blockDim.x + threadIdx.x;
    if (g >= NB * MM) return;
    int b = g / MM;
    unsigned long long gk = sorted[g];
    float4 bx = make_float4(0.f, 0.f, 0.f, 0.f);
    float sc = 0.f, cf = 0.f;
    unsigned int v = 0;
    if (gk) {
        sc = __uint_as_float((unsigned int)(gk >> 34));
        int l = 7 - (int)((gk >> 31) & 7);
        int idx = (int)(gk & 0x1FFFFF);
        int loc = idx / 80;
        int c = idx - loc * 80;
        int gl = d_lstart[l] + loc;
        float lx = locs[gl * 2], ly = locs[gl * 2 + 1];
        const float* r4 = reg + ((long long)b * NLOC + gl) * 4;
        float x1 = fminf(fmaxf(lx - r4[0], 0.f), 1024.f);
        float y1 = fminf(fmaxf(ly - r4[1], 0.f), 1024.f);
        float x2 = fminf(fmaxf(lx + r4[2], 0.f), 1024.f);
        float y2 = fminf(fmaxf(ly + r4[3], 0.f), 1024.f);
        bx = make_float4(x1, y1, x2, y2);
        cf = (float)(c + 1);
        v = 1;
    }
    boxesWS[g] = bx;
    scoresWS[g] = sc;
    clsWS[g] = cf;
    validWS[g] = v;
}

// ---------------- Kernel M: pairwise suppression bitmask (j>i, iou>0.6) ----------------
// mask row i, word w (>= i>>6) : bit jj set iff j=w*64+jj suppressible by i.
// Words w < i>>6 are left UNWRITTEN (scan gates them out).
__global__ __launch_bounds__(256) void k_mask(const float4* __restrict__ boxesWS,
                                              unsigned long long* __restrict__ mask) {
    int bid = blockIdx.x;
    int b = bid / 20, chunk = bid % 20;
    int t = threadIdx.x;
    int i = chunk * 256 + t;
    bool active = i < MM;
    __shared__ float4 cb[1024];
    __shared__ float ca[1024];
    float4 hb = make_float4(0.f, 0.f, 0.f, 0.f);
    float hA = 0.f;
    int iw0 = 0;
    if (active) {
        hb = boxesWS[b * MM + i];
        hA = (hb.z - hb.x) * (hb.w - hb.y);
        iw0 = i >> 6;
    }
    unsigned long long* Mrow = mask + ((size_t)b * MROWS + (size_t)min(i, MM - 1)) * 80;
    for (int wblk = 0; wblk < 5; ++wblk) {
        int c0 = wblk * 1024;
        __syncthreads();
        for (int c = t; c < 1024; c += 256) {
            int j = c0 + c;
            float4 v = (j < MM) ? boxesWS[b * MM + j] : make_float4(0.f, 0.f, 0.f, 0.f);
            cb[c] = v;
            ca[c] = (v.z - v.x) * (v.w - v.y);
        }
        __syncthreads();
        if (active) {
            int wlo = (iw0 > wblk * 16) ? iw0 : wblk * 16;
            for (int w = wlo; w < wblk * 16 + 16; ++w) {
                unsigned long long m = 0ULL;
                int jbase = w * 64;
                for (int jj = 0; jj < 64; ++jj) {
                    int j = jbase + jj;
                    if (j > i && j < MM) {
                        float4 cbj = cb[j - c0];
                        float xi1 = fmaxf(hb.x, cbj.x);
                        float yi1 = fmaxf(hb.y, cbj.y);
                        float xi2 = fminf(hb.z, cbj.z);
                        float yi2 = fminf(hb.w, cbj.w);
                        float inter = fmaxf(xi2 - xi1, 0.f) * fmaxf(yi2 - yi1, 0.f);
                        float iou = inter / fmaxf(hA + ca[j - c0] - inter, 1e-9f);
                        if (iou > 0.6f) m |= 1ULL << jj;
                    }
                }
                Mrow[w] = m;
            }
        }
    }
}

// ---------------- Kernel S: serial bitmask scan (1 wave per batch) ----------------
// removed words distributed: lane owns w=lane (r0) and w=lane+64 if lane<16 (r1).
// Replicated diagonal word dcur keeps the per-iteration critical path register-only.
#define ISSUE(X0, X1, XD, g)                                                        \
    do {                                                                            \
        if ((g) < 314) {                                                            \
            int iw_ = (g) >> 2;                                                     \
            const unsigned long long* rp_ = M + (size_t)(g) * 1280;                 \
            _Pragma("unroll") for (int k = 0; k < 16; ++k) {                        \
                X0[k] = rp_[(size_t)k * 80 + lane];                                 \
                X1[k] = (lane < 16) ? rp_[(size_t)k * 80 + 64 + lane] : 0ULL;       \
                XD[k] = rp_[(size_t)k * 80 + iw_];                                  \
            }                                                                       \
        }                                                                           \
    } while (0)

#define CONSUME(X0, X1, XD, g)                                                      \
    do {                                                                            \
        int base_ = (g) * 16;                                                       \
        _Pragma("unroll") for (int k = 0; k < 16; ++k) {                            \
            int sh_ = (base_ + k) & 63;                                             \
            unsigned long long m_ = (((dcur >> sh_) & 1ULL) == 0ULL) ? ~0ULL : 0ULL;\
            dcur |= XD[k] & m_;                                                     \
            r0 |= X0[k] & m_ & gmask0;                                              \
            r1 |= X1[k] & m_ & gmask1;                                              \
        }                                                                           \
    } while (0)

__device__ __forceinline__ unsigned long long shfl_u64(unsigned long long v, int src) {
    int lo = __shfl((int)(unsigned int)v, src, 64);
    int hi = __shfl((int)(unsigned int)(v >> 32), src, 64);
    return ((unsigned long long)(unsigned int)hi << 32) | (unsigned int)lo;
}

#define RESYNC(g)                                                                   \
    do {                                                                            \
        int iw_ = (g) >> 2;                                                         \
        unsigned long long src_ = (iw_ < 64) ? r0 : r1;                             \
        dcur = shfl_u64(src_, iw_ & 63);                                            \
        gmask0 = (lane >= iw_) ? ~0ULL : 0ULL;                                      \
        gmask1 = (lane < 16 && (lane + 64) >= iw_) ? ~0ULL : 0ULL;                  \
    } while (0)

__global__ __launch_bounds__(64) void k_scan(const unsigned int* __restrict__ validWS,
                                             const unsigned long long* __restrict__ mask,
                                             const float* __restrict__ scoresWS,
                                             unsigned long long* __restrict__ keepw,
                                             float* __restrict__ threshB) {
    int b = blockIdx.x;
    int lane = threadIdx.x;
    const unsigned long long* M = mask + (size_t)b * MROWS * 80;
    unsigned long long r0 = 0ULL, r1 = 0ULL;
    {
        int w0 = lane;
#pragma unroll 8
        for (int jj = 0; jj < 64; ++jj) {
            int j = w0 * 64 + jj;
            unsigned int v = (j < MM) ? validWS[b * MM + j] : 0u;
            r0 |= (unsigned long long)(v ? 0u : 1u) << jj;
        }
        if (lane < 16) {
            int w1 = lane + 64;
#pragma unroll 8
            for (int jj = 0; jj < 64; ++jj) {
                int j = w1 * 64 + jj;
                unsigned int v = (j < MM) ? validWS[b * MM + j] : 0u;
                r1 |= (unsigned long long)(v ? 0u : 1u) << jj;
            }
        }
    }
    unsigned long long A0[16], A1[16], AD[16], B0[16], B1[16], BD[16];
    unsigned long long dcur = 0ULL, gmask0 = 0ULL, gmask1 = 0ULL;
    ISSUE(A0, A1, AD, 0);
    ISSUE(B0, B1, BD, 1);
    for (int g = 0; g < 314; g += 2) {
        if ((g & 3) == 0) RESYNC(g);
        CONSUME(A0, A1, AD, g);
        ISSUE(A0, A1, AD, g + 2);
        CONSUME(B0, B1, BD, g + 1);
        ISSUE(B0, B1, BD, g + 3);
    }
    // post-select
    __shared__ unsigned long long kw[80];
    unsigned long long k0 = ~r0;
    kw[lane] = k0;
    keepw[b * 80 + lane] = k0;
    if (lane < 16) {
        unsigned long long k1 = ~r1;
        kw[64 + lane] = k1;
        keepw[b * 80 + 64 + lane] = k1;
    }
    __syncthreads();
    if (lane == 0) {
        int ndet = 0;
        for (int w = 0; w < 80; ++w) ndet += __popcll(kw[w]);
        float th = -INFINITY;
        if (ndet > 100) {
            int cum = 0, pos = -1;
            for (int w = 0; w < 80 && pos < 0; ++w) {
                int c = __popcll(kw[w]);
                if (cum + c >= 100) {
                    unsigned long long word = kw[w];
                    for (int bb = 0; bb < 64; ++bb) {
                        cum += (int)((word >> bb) & 1ULL);
                        if (cum == 100) { pos = w * 64 + bb; break; }
                    }
                } else {
                    cum += c;
                }
            }
            th = scoresWS[b * MM + pos];
        }
        threshB[b] = th;
    }
}

// ---------------- Kernel Z: masked output write ----------------
__global__ void k_final(const float4* __restrict__ boxesWS, const float* __restrict__ scoresWS,
                        const float* __restrict__ clsWS, const unsigned long long* __restrict__ keepw,
                        const float* __restrict__ threshB, float* __restrict__ out) {
    int g = blockIdx.x * blockDim.x + threadIdx.x;
    if (g >= NB * MM) return;
    int b = g / MM;
    int p = g - b * MM;
    bool kb = (keepw[b * 80 + (p >> 6)] >> (p & 63)) & 1ULL;
    float s = scoresWS[g];
    float th = threshB[b];
    bool k = kb && (s >= th) && (s >= 0.05f);
    float km = k ? 1.0f : 0.0f;
    float4 v = boxesWS[g];
    float* ob = out;
    float* os = out + NB * MM * 4;
    float* oc = out + NB * MM * 5;
    float* ok = out + NB * MM * 6;
    ((float4*)ob)[g] = make_float4(v.x * km, v.y * km, v.z * km, v.w * km);
    os[g] = s * km;
    oc[g] = clsWS[g] * km;
    ok[g] = km;
}

// ---------------- Fallback: old sequential NMS (used only if ws too small) ----------------
__global__ __launch_bounds__(1024) void k_nms(const float4* __restrict__ boxesWS,
                                              const float* __restrict__ scoresWS,
                                              const float* __restrict__ clsWS,
                                              const unsigned int* __restrict__ validWS,
                                              float* __restrict__ out) {
    int b = blockIdx.x;
    int t = threadIdx.x;
    __shared__ unsigned char kf[MM];
    __shared__ int s_min;
    __shared__ int s_cnt;
    float4 bx[5];
    float ar[5];
    int base = b * MM;
    for (int c = 0; c < 5; c++) {
        int p = t + 1024 * c;
        bx[c] = make_float4(0.f, 0.f, 0.f, 0.f);
        ar[c] = 0.f;
        if (p < MM) {
            kf[p] = (unsigned char)validWS[base + p];
            float4 v = boxesWS[base + p];
            bx[c] = v;
            ar[c] = (v.z - v.x) * (v.w - v.y);
        }
    }
    __syncthreads();
    int i = -1;
    while (true) {
        int nh = -1;
        int wstart = i + 1;
        while (wstart < MM) {
            if (t == 0) s_min = 0x7FFFFFFF;
            __syncthreads();
            int p = wstart + t;
            if (p < MM && kf[p]) atomicMin(&s_min, p);
            __syncthreads();
            int sm = s_min;
            __syncthreads();
            if (sm != 0x7FFFFFFF) { nh = sm; break; }
            wstart += 1024;
        }
        if (nh < 0) break;
        i = nh;
        float4 hb = boxesWS[base + i];
        float ha = (hb.z - hb.x) * (hb.w - hb.y);
        for (int c = 0; c < 5; c++) {
            int p = t + 1024 * c;
            if (p > i && p < MM && kf[p]) {
                float xi1 = fmaxf(hb.x, bx[c].x);
                float yi1 = fmaxf(hb.y, bx[c].y);
                float xi2 = fminf(hb.z, bx[c].z);
                float yi2 = fminf(hb.w, bx[c].w);
                float inter = fmaxf(xi2 - xi1, 0.f) * fmaxf(yi2 - yi1, 0.f);
                float iou = inter / fmaxf(ha + ar[c] - inter, 1e-9f);
                if (iou > 0.6f) kf[p] = 0;
            }
        }
        __syncthreads();
    }
    if (t == 0) s_cnt = 0;
    __syncthreads();
    int lc = 0;
    for (int c = 0; c < 5; c++) {
        int p = t + 1024 * c;
        if (p < MM && kf[p]) lc++;
    }
    if (lc) atomicAdd(&s_cnt, lc);
    __syncthreads();
    int n_det = s_cnt;
    float thresh = -INFINITY;
    if (n_det > 100) {
        int lo = 0, hi = MM - 1;
        while (lo < hi) {
            int mid = (lo + hi) >> 1;
            __syncthreads();
            if (t == 0) s_cnt = 0;
            __syncthreads();
            int c2 = 0;
            for (int c = 0; c < 5; c++) {
                int p = t + 1024 * c;
                if (p < MM && p <= mid && kf[p]) c2++;
            }
            if (c2) atomicAdd(&s_cnt, c2);
            __syncthreads();
            if (s_cnt >= 100) hi = mid; else lo = mid + 1;
            __syncthreads();
        }
        thresh = scoresWS[base + lo];
    }
    float* ob = out;
    float* os = out + NB * MM * 4;
    float* oc = out + NB * MM * 5;
    float* ok = out + NB * MM * 6;
    for (int c = 0; c < 5; c++) {
        int p = t + 1024 * c;
        if (p < MM) {
            int g = base + p;
            float s = scoresWS[g];
            bool k = kf[p] && (s >= thresh) && (s >= 0.05f);
            float km = k ? 1.0f : 0.0f;
            float4 v = bx[c];
            ((float4*)ob)[g] = make_float4(v.x * km, v.y * km, v.z * km, v.w * km);
            os[g] = s * km;
            oc[g] = clsWS[g] * km;
            ok[g] = km;
        }
    }
}

extern "C" void kernel_launch(void* const* d_in, const int* in_sizes, int n_in,
                              void* d_out, int out_size, void* d_ws, size_t ws_size,
                              hipStream_t stream) {
    const float* cls = (const float*)d_in[0];
    const float* reg = (const float*)d_in[1];
    const float* ctr = (const float*)d_in[2];
    const float* locs = (const float*)d_in[3];
    (void)in_sizes; (void)n_in; (void)out_size;

    char* ws = (char*)d_ws;
    // layout (256-aligned)
    unsigned int* hist = (unsigned int*)(ws);                            // 10,485,760
    unsigned int* cnt = (unsigned int*)(ws + 10485760);                  // 512
    unsigned int* bcut = (unsigned int*)(ws + 10486272);                 // 512
    unsigned long long* compact = (unsigned long long*)(ws + 10486784);  // 2,621,440
    unsigned long long* pool = (unsigned long long*)(ws + 13108224);     // 640,000
    unsigned long long* sorted = (unsigned long long*)(ws + 13748224);   // 640,000
    float4* boxesWS = (float4*)(ws + 14388224);                          // 1,280,000
    float* scoresWS = (float*)(ws + 15668224);                           // 320,000
    float* clsWS = (float*)(ws + 15988224);                              // 320,000
    unsigned int* validWS = (unsigned int*)(ws + 16308224);              // 320,000
    unsigned long long* keepw = (unsigned long long*)(ws + 16628224);    // 10,240
    float* threshB = (float*)(ws + 16638464);                            // 256
    unsigned long long* mask = (unsigned long long*)(ws + 16638720);     // 51,445,760
    const size_t WS_NEED = 16638720ULL + 51445760ULL;                    // 68,084,480

    hipMemsetAsync(ws, 0, 10486784, stream);  // hist + cnt + bcut
    hipLaunchKernelGGL(k_hist, dim3(4096), dim3(256), 0, stream, cls, ctr, hist);
    hipLaunchKernelGGL(k_cutoff, dim3(80), dim3(256), 0, stream, hist, bcut);
    hipLaunchKernelGGL(k_compact, dim3(4096), dim3(256), 0, stream, cls, ctr, bcut, cnt, compact);
    hipLaunchKernelGGL(k_select, dim3(80), dim3(1024), 0, stream, cnt, compact, pool);
    hipLaunchKernelGGL(k_gsort, dim3(16), dim3(1024), 0, stream, pool, sorted);
    hipLaunchKernelGGL(k_decode, dim3((NB * MM + 255) / 256), dim3(256), 0, stream,
                       sorted, reg, locs, boxesWS, scoresWS, clsWS, validWS);
    if (ws_size >= WS_NEED) {
        hipLaunchKernelGGL(k_mask, dim3(NB * 20), dim3(256), 0, stream, boxesWS, mask);
        hipLaunchKernelGGL(k_scan, dim3(NB), dim3(64), 0, stream,
                           validWS, mask, scoresWS, keepw, threshB);
        hipLaunchKernelGGL(k_final, dim3((NB * MM + 511) / 512), dim3(512), 0, stream,
                           boxesWS, scoresWS, clsWS, keepw, threshB, (float*)d_out);
    } else {
        hipLaunchKernelGGL(k_nms, dim3(NB), dim3(1024), 0, stream,
                           boxesWS, scoresWS, clsWS, validWS, (float*)d_out);
    }
}

// Round 4
// 1766.427 us; speedup vs baseline: 3.8228x; 1.4085x over previous
//
#include <hip/hip_runtime.h>
#include <math.h>

#define NB 16
#define NLOC 21824
#define NCLS 80
#define NLVL 5
#define MM 5000
#define MROWS 5024      // MM padded for scan groups (314 groups of 16)
#define CAP 4096
#define EPB 1745920     // entries per batch = NLOC*NCLS

__device__ __forceinline__ int level_of(int r) {
    return (r < 1310720) ? 0 : (r < 1638400) ? 1 : (r < 1720320) ? 2 : (r < 1740800) ? 3 : 4;
}
__device__ __constant__ int d_estart[5] = {0, 1310720, 1638400, 1720320, 1740800};
__device__ __constant__ int d_lstart[5] = {0, 16384, 20480, 21504, 21760};
// k_mask block map: per-batch 110 blocks; start offset per row-chunk rc (cg_min = rc/2)
__device__ __constant__ int d_mstart[20] = {0,10,20,29,38,46,54,61,68,74,80,85,90,94,98,101,104,106,108,109};

// ---------------- Kernel A: per-(b,l) 15-bit histogram of candidate valbits ----------------
__global__ void k_hist(const float* __restrict__ cls, const float* __restrict__ ctr,
                       unsigned int* __restrict__ hist) {
    const long long total = (long long)NB * EPB;
    for (long long e = (long long)blockIdx.x * blockDim.x + threadIdx.x; e < total;
         e += (long long)gridDim.x * blockDim.x) {
        float x = cls[e];
        if (x <= -2.945f) continue;  // sigmoid(-2.945)=0.049968 < 0.05f, safe prescreen
        double sd = 1.0 / (1.0 + exp(-(double)x));
        float sf = (float)sd;
        if (!(sf > 0.05f)) continue;
        int b = (int)(e / EPB);
        int r = (int)(e - (long long)b * EPB);
        int l = level_of(r);
        int locg = r / 80;
        float c = ctr[(long long)b * NLOC + locg];
        double cd = 1.0 / (1.0 + exp(-(double)c));
        float val = sf * (float)cd;
        unsigned int vb = __float_as_uint(val);
        atomicAdd(&hist[(((long long)b * 5 + l) << 15) + (vb >> 15)], 1u);
    }
}

// ---------------- Kernel B: find cutoff bucket per (b,l) ----------------
__global__ void k_cutoff(const unsigned int* __restrict__ hist, unsigned int* __restrict__ bcut) {
    int g = blockIdx.x;  // 0..79
    const unsigned int* h = hist + ((long long)g << 15);
    __shared__ unsigned int ssum[256];
    int t = threadIdx.x;
    unsigned int s = 0;
    for (int i = 0; i < 128; i++) s += h[t * 128 + i];
    ssum[t] = s;
    __syncthreads();
    if (t == 0) {
        unsigned int cum = 0;
        int bucket = 0;
        int ch = 255;
        for (; ch >= 0; ch--) {
            if (cum + ssum[ch] >= 1000u) break;
            cum += ssum[ch];
        }
        if (ch >= 0) {
            int bi = ch * 128 + 127;
            for (; bi > ch * 128; bi--) {
                unsigned int c = h[bi];
                if (cum + c >= 1000u) break;
                cum += c;
            }
            bucket = bi;
        }
        bcut[g] = (unsigned int)bucket;
    }
}

// ---------------- Kernel C: compact candidates >= cutoff bucket ----------------
__global__ void k_compact(const float* __restrict__ cls, const float* __restrict__ ctr,
                          const unsigned int* __restrict__ bcut, unsigned int* __restrict__ cnt,
                          unsigned long long* __restrict__ compact) {
    const long long total = (long long)NB * EPB;
    for (long long e = (long long)blockIdx.x * blockDim.x + threadIdx.x; e < total;
         e += (long long)gridDim.x * blockDim.x) {
        float x = cls[e];
        if (x <= -2.945f) continue;
        double sd = 1.0 / (1.0 + exp(-(double)x));
        float sf = (float)sd;
        if (!(sf > 0.05f)) continue;
        int b = (int)(e / EPB);
        int r = (int)(e - (long long)b * EPB);
        int l = level_of(r);
        int locg = r / 80;
        float c = ctr[(long long)b * NLOC + locg];
        double cd = 1.0 / (1.0 + exp(-(double)c));
        float val = sf * (float)cd;
        unsigned int vb = __float_as_uint(val);
        int g = b * 5 + l;
        if ((vb >> 15) >= bcut[g]) {
            unsigned int pos = atomicAdd(&cnt[g], 1u);
            if (pos < CAP) {
                unsigned int idx = (unsigned int)(r - d_estart[l]);
                compact[(long long)g * CAP + pos] =
                    ((unsigned long long)vb << 21) | (unsigned long long)(0x1FFFFFu - idx);
            }
        }
    }
}

// ---------------- Kernel D: per-(b,l) bitonic sort + build global keys ----------------
__global__ void k_select(const unsigned int* __restrict__ cnt,
                         const unsigned long long* __restrict__ compact,
                         unsigned long long* __restrict__ pool) {
    __shared__ unsigned long long sk[CAP];
    int g = blockIdx.x;
    int b = g / 5, l = g % 5;
    int count = min((int)cnt[g], CAP);
    for (int p = threadIdx.x; p < CAP; p += blockDim.x)
        sk[p] = (p < count) ? compact[(long long)g * CAP + p] : 0ULL;
    __syncthreads();
    for (int k = 2; k <= CAP; k <<= 1) {
        for (int j = k >> 1; j > 0; j >>= 1) {
            for (int i = threadIdx.x; i < CAP; i += blockDim.x) {
                int ixj = i ^ j;
                if (ixj > i) {
                    unsigned long long a = sk[i], bb = sk[ixj];
                    bool desc = ((i & k) == 0);
                    if (desc ? (a < bb) : (a > bb)) { sk[i] = bb; sk[ixj] = a; }
                }
            }
            __syncthreads();
        }
    }
    int ksel = min(1000, count);
    for (int r = threadIdx.x; r < 1000; r += blockDim.x) {
        unsigned long long gk = 0ULL;
        if (r < ksel) {
            unsigned long long key = sk[r];
            unsigned int vb = (unsigned int)(key >> 21);
            unsigned int idx = 0x1FFFFFu - (unsigned int)(key & 0x1FFFFFu);
            float val = __uint_as_float(vb);
            float sc = sqrtf(val);
            unsigned long long sb = (unsigned long long)__float_as_uint(sc);
            gk = (sb << 34) | ((unsigned long long)(7 - l) << 31) |
                 ((unsigned long long)(1023 - r) << 21) | (unsigned long long)idx;
        }
        pool[(long long)b * MM + l * 1000 + r] = gk;
    }
}

// ---------------- Kernel E': 5-way merge by exact rank (replaces 8192 bitonic) ----------------
// Keys are unique (level+rank+idx bits); rank(K) = own index + sum over other lists of
// count(> K) via binary search on the descending lists. Zeros (empty slots) get
// deterministic tail ranks. Produces the identical permutation to a full descending sort.
__global__ __launch_bounds__(1024) void k_merge(const unsigned long long* __restrict__ pool,
                                                const unsigned int* __restrict__ cnt,
                                                unsigned long long* __restrict__ sorted) {
    __shared__ unsigned long long sp[MM];
    __shared__ int s_nz[5];
    int b = blockIdx.x, t = threadIdx.x;
    for (int p = t; p < MM; p += 1024) sp[p] = pool[(long long)b * MM + p];
    if (t < 5) s_nz[t] = (int)min(cnt[b * 5 + t], 1000u);
    __syncthreads();
    int nzTot = s_nz[0] + s_nz[1] + s_nz[2] + s_nz[3] + s_nz[4];
    for (int p = t; p < MM; p += 1024) {
        int l = p / 1000, r = p - l * 1000;
        unsigned long long K = sp[p];
        int rank;
        if (K) {
            rank = r;  // elements before r in own descending list are all > K
#pragma unroll
            for (int l2 = 0; l2 < 5; ++l2) {
                if (l2 == l) continue;
                const unsigned long long* L = sp + l2 * 1000;
                int lo = 0, hi = s_nz[l2];
                while (lo < hi) {
                    int mid = (lo + hi) >> 1;
                    if (L[mid] > K) lo = mid + 1; else hi = mid;
                }
                rank += lo;
            }
        } else {
            int zi = 0;
#pragma unroll
            for (int l2 = 0; l2 < 5; ++l2) if (l2 < l) zi += 1000 - s_nz[l2];
            zi += r - s_nz[l];
            rank = nzTot + zi;
        }
        sorted[(long long)b * MM + rank] = K;
    }
}

// ---------------- Kernel F: decode boxes/scores/classes ----------------
__global__ void k_decode(const unsigned long long* __restrict__ sorted,
                         const float* __restrict__ reg, const float* __restrict__ locs,
                         float4* __restrict__ boxesWS, float* __restrict__ scoresWS,
                         float* __restrict__ clsWS, unsigned int* __restrict__ validWS) {
    int g = blockIdx.x * blockDim.x + threadIdx.x;
    if (g >= NB * MM) return;
    int b = g / MM;
    unsigned long long gk = sorted[g];
    float4 bx = make_float4(0.f, 0.f, 0.f, 0.f);
    float sc = 0.f, cf = 0.f;
    unsigned int v = 0;
    if (gk) {
        sc = __uint_as_float((unsigned int)(gk >> 34));
        int l = 7 - (int)((gk >> 31) & 7);
        int idx = (int)(gk & 0x1FFFFF);
        int loc = idx / 80;
        int c = idx - loc * 80;
        int gl = d_lstart[l] + loc;
        float lx = locs[gl * 2], ly = locs[gl * 2 + 1];
        const float* r4 = reg + ((long long)b * NLOC + gl) * 4;
        float x1 = fminf(fmaxf(lx - r4[0], 0.f), 1024.f);
        float y1 = fminf(fmaxf(ly - r4[1], 0.f), 1024.f);
        float x2 = fminf(fmaxf(lx + r4[2], 0.f), 1024.f);
        float y2 = fminf(fmaxf(ly + r4[3], 0.f), 1024.f);
        bx = make_float4(x1, y1, x2, y2);
        cf = (float)(c + 1);
        v = 1;
    }
    boxesWS[g] = bx;
    scoresWS[g] = sc;
    clsWS[g] = cf;
    validWS[g] = v;
}

// ---------------- Kernel M: pairwise suppression bitmask (tiled, high-occupancy) ----------------
// Block = (batch b, row-chunk rc of 256 rows, col-group cg of 512 cols), cg >= rc/2.
// Thread t handles row i = rc*256+t: computes 8 mask words (cols cg*512..+511),
// writes them as one contiguous 64B span (no write amplification).
// Words w < i>>6 are left unwritten (k_scan gates them); diagonal word masked to j>i.
__global__ __launch_bounds__(256) void k_mask(const float4* __restrict__ boxesWS,
                                              unsigned long long* __restrict__ mask) {
    __shared__ float4 cb[512];
    __shared__ float ca[512];
    int id = blockIdx.x;
    int b = id / 110;
    int q = id - b * 110;
    int rc = 19;
    for (int r = 1; r < 20; ++r) if (q < d_mstart[r]) { rc = r - 1; break; }
    int cg = rc / 2 + (q - d_mstart[rc]);
    int t = threadIdx.x;
    int i = rc * 256 + t;
    int c0 = cg * 512;
    // stage 512 column boxes
    for (int c = t; c < 512; c += 256) {
        int j = c0 + c;
        float4 v = (j < MM) ? boxesWS[b * MM + j] : make_float4(0.f, 0.f, 0.f, 0.f);
        cb[c] = v;
        ca[c] = (v.z - v.x) * (v.w - v.y);
    }
    __syncthreads();
    if (i >= MM) return;
    float4 hb = boxesWS[b * MM + i];
    float hA = (hb.z - hb.x) * (hb.w - hb.y);
    int iw0 = i >> 6;
    int cg8 = cg * 8;
    unsigned long long wbuf[8];
#pragma unroll
    for (int k = 0; k < 8; ++k) {
        int w = cg8 + k;
        unsigned long long m = 0ULL;
        if (w >= iw0) {
            int cbase = w * 64 - c0;
            for (int jj = 0; jj < 64; ++jj) {
                float4 cbj = cb[cbase + jj];
                float xi1 = fmaxf(hb.x, cbj.x);
                float yi1 = fmaxf(hb.y, cbj.y);
                float xi2 = fminf(hb.z, cbj.z);
                float yi2 = fminf(hb.w, cbj.w);
                float inter = fmaxf(xi2 - xi1, 0.f) * fmaxf(yi2 - yi1, 0.f);
                float iou = inter / fmaxf(hA + ca[cbase + jj] - inter, 1e-9f);
                if (iou > 0.6f) m |= 1ULL << jj;
            }
            if (w == iw0) m &= (0xFFFFFFFFFFFFFFFEULL << (i & 63));  // keep only j > i
        }
        wbuf[k] = m;
    }
    unsigned long long* Mrow = mask + ((size_t)b * MROWS + (size_t)i) * 80 + cg8;
    if (iw0 <= cg8) {
        // full 8-word span, 64B contiguous, 16B-aligned
        ((ulonglong2*)Mrow)[0] = make_ulonglong2(wbuf[0], wbuf[1]);
        ((ulonglong2*)Mrow)[1] = make_ulonglong2(wbuf[2], wbuf[3]);
        ((ulonglong2*)Mrow)[2] = make_ulonglong2(wbuf[4], wbuf[5]);
        ((ulonglong2*)Mrow)[3] = make_ulonglong2(wbuf[6], wbuf[7]);
    } else {
#pragma unroll
        for (int k = 0; k < 8; ++k)
            if (cg8 + k >= iw0) Mrow[k] = wbuf[k];
    }
}

// ---------------- Kernel S: serial bitmask scan (1 wave per batch) ----------------
#define ISSUE(X0, X1, XD, g)                                                        \
    do {                                                                            \
        if ((g) < 314) {                                                            \
            int iw_ = (g) >> 2;                                                     \
            const unsigned long long* rp_ = M + (size_t)(g) * 1280;                 \
            _Pragma("unroll") for (int k = 0; k < 16; ++k) {                        \
                X0[k] = rp_[(size_t)k * 80 + lane];                                 \
                X1[k] = (lane < 16) ? rp_[(size_t)k * 80 + 64 + lane] : 0ULL;       \
                XD[k] = rp_[(size_t)k * 80 + iw_];                                  \
            }                                                                       \
        }                                                                           \
    } while (0)

#define CONSUME(X0, X1, XD, g)                                                      \
    do {                                                                            \
        int base_ = (g) * 16;                                                       \
        _Pragma("unroll") for (int k = 0; k < 16; ++k) {                            \
            int sh_ = (base_ + k) & 63;                                             \
            unsigned long long m_ = (((dcur >> sh_) & 1ULL) == 0ULL) ? ~0ULL : 0ULL;\
            dcur |= XD[k] & m_;                                                     \
            r0 |= X0[k] & m_ & gmask0;                                              \
            r1 |= X1[k] & m_ & gmask1;                                              \
        }                                                                           \
    } while (0)

__device__ __forceinline__ unsigned long long shfl_u64(unsigned long long v, int src) {
    int lo = __shfl((int)(unsigned int)v, src, 64);
    int hi = __shfl((int)(unsigned int)(v >> 32), src, 64);
    return ((unsigned long long)(unsigned int)hi << 32) | (unsigned int)lo;
}

#define RESYNC(g)                                                                   \
    do {                                                                            \
        int iw_ = (g) >> 2;                                                         \
        unsigned long long src_ = (iw_ < 64) ? r0 : r1;                             \
        dcur = shfl_u64(src_, iw_ & 63);                                            \
        gmask0 = (lane >= iw_) ? ~0ULL : 0ULL;                                      \
        gmask1 = (lane < 16 && (lane + 64) >= iw_) ? ~0ULL : 0ULL;                  \
    } while (0)

__global__ __launch_bounds__(64) void k_scan(const unsigned int* __restrict__ validWS,
                                             const unsigned long long* __restrict__ mask,
                                             const float* __restrict__ scoresWS,
                                             unsigned long long* __restrict__ keepw,
                                             float* __restrict__ threshB) {
    int b = blockIdx.x;
    int lane = threadIdx.x;
    const unsigned long long* M = mask + (size_t)b * MROWS * 80;
    unsigned long long r0 = 0ULL, r1 = 0ULL;
    {
        int w0 = lane;
#pragma unroll 8
        for (int jj = 0; jj < 64; ++jj) {
            int j = w0 * 64 + jj;
            unsigned int v = (j < MM) ? validWS[b * MM + j] : 0u;
            r0 |= (unsigned long long)(v ? 0u : 1u) << jj;
        }
        if (lane < 16) {
            int w1 = lane + 64;
#pragma unroll 8
            for (int jj = 0; jj < 64; ++jj) {
                int j = w1 * 64 + jj;
                unsigned int v = (j < MM) ? validWS[b * MM + j] : 0u;
                r1 |= (unsigned long long)(v ? 0u : 1u) << jj;
            }
        }
    }
    unsigned long long A0[16], A1[16], AD[16], B0[16], B1[16], BD[16];
    unsigned long long dcur = 0ULL, gmask0 = 0ULL, gmask1 = 0ULL;
    ISSUE(A0, A1, AD, 0);
    ISSUE(B0, B1, BD, 1);
    for (int g = 0; g < 314; g += 2) {
        if ((g & 3) == 0) RESYNC(g);
        CONSUME(A0, A1, AD, g);
        ISSUE(A0, A1, AD, g + 2);
        CONSUME(B0, B1, BD, g + 1);
        ISSUE(B0, B1, BD, g + 3);
    }
    // post-select
    __shared__ unsigned long long kw[80];
    unsigned long long k0 = ~r0;
    kw[lane] = k0;
    keepw[b * 80 + lane] = k0;
    if (lane < 16) {
        unsigned long long k1 = ~r1;
        kw[64 + lane] = k1;
        keepw[b * 80 + 64 + lane] = k1;
    }
    __syncthreads();
    if (lane == 0) {
        int ndet = 0;
        for (int w = 0; w < 80; ++w) ndet += __popcll(kw[w]);
        float th = -INFINITY;
        if (ndet > 100) {
            int cum = 0, pos = -1;
            for (int w = 0; w < 80 && pos < 0; ++w) {
                int c = __popcll(kw[w]);
                if (cum + c >= 100) {
                    unsigned long long word = kw[w];
                    for (int bb = 0; bb < 64; ++bb) {
                        cum += (int)((word >> bb) & 1ULL);
                        if (cum == 100) { pos = w * 64 + bb; break; }
                    }
                } else {
                    cum += c;
                }
            }
            th = scoresWS[b * MM + pos];
        }
        threshB[b] = th;
    }
}

// ---------------- Kernel Z: masked output write ----------------
__global__ void k_final(const float4* __restrict__ boxesWS, const float* __restrict__ scoresWS,
                        const float* __restrict__ clsWS, const unsigned long long* __restrict__ keepw,
                        const float* __restrict__ threshB, float* __restrict__ out) {
    int g = blockIdx.x * blockDim.x + threadIdx.x;
    if (g >= NB * MM) return;
    int b = g / MM;
    int p = g - b * MM;
    bool kb = (keepw[b * 80 + (p >> 6)] >> (p & 63)) & 1ULL;
    float s = scoresWS[g];
    float th = threshB[b];
    bool k = kb && (s >= th) && (s >= 0.05f);
    float km = k ? 1.0f : 0.0f;
    float4 v = boxesWS[g];
    float* ob = out;
    float* os = out + NB * MM * 4;
    float* oc = out + NB * MM * 5;
    float* ok = out + NB * MM * 6;
    ((float4*)ob)[g] = make_float4(v.x * km, v.y * km, v.z * km, v.w * km);
    os[g] = s * km;
    oc[g] = clsWS[g] * km;
    ok[g] = km;
}

// ---------------- Fallback: sequential NMS (used only if ws too small) ----------------
__global__ __launch_bounds__(1024) void k_nms(const float4* __restrict__ boxesWS,
                                              const float* __restrict__ scoresWS,
                                              const float* __restrict__ clsWS,
                                              const unsigned int* __restrict__ validWS,
                                              float* __restrict__ out) {
    int b = blockIdx.x;
    int t = threadIdx.x;
    __shared__ unsigned char kf[MM];
    __shared__ int s_min;
    __shared__ int s_cnt;
    float4 bx[5];
    float ar[5];
    int base = b * MM;
    for (int c = 0; c < 5; c++) {
        int p = t + 1024 * c;
        bx[c] = make_float4(0.f, 0.f, 0.f, 0.f);
        ar[c] = 0.f;
        if (p < MM) {
            kf[p] = (unsigned char)validWS[base + p];
            float4 v = boxesWS[base + p];
            bx[c] = v;
            ar[c] = (v.z - v.x) * (v.w - v.y);
        }
    }
    __syncthreads();
    int i = -1;
    while (true) {
        int nh = -1;
        int wstart = i + 1;
        while (wstart < MM) {
            if (t == 0) s_min = 0x7FFFFFFF;
            __syncthreads();
            int p = wstart + t;
            if (p < MM && kf[p]) atomicMin(&s_min, p);
            __syncthreads();
            int sm = s_min;
            __syncthreads();
            if (sm != 0x7FFFFFFF) { nh = sm; break; }
            wstart += 1024;
        }
        if (nh < 0) break;
        i = nh;
        float4 hb = boxesWS[base + i];
        float ha = (hb.z - hb.x) * (hb.w - hb.y);
        for (int c = 0; c < 5; c++) {
            int p = t + 1024 * c;
            if (p > i && p < MM && kf[p]) {
                float xi1 = fmaxf(hb.x, bx[c].x);
                float yi1 = fmaxf(hb.y, bx[c].y);
                float xi2 = fminf(hb.z, bx[c].z);
                float yi2 = fminf(hb.w, bx[c].w);
                float inter = fmaxf(xi2 - xi1, 0.f) * fmaxf(yi2 - yi1, 0.f);
                float iou = inter / fmaxf(ha + ar[c] - inter, 1e-9f);
                if (iou > 0.6f) kf[p] = 0;
            }
        }
        __syncthreads();
    }
    if (t == 0) s_cnt = 0;
    __syncthreads();
    int lc = 0;
    for (int c = 0; c < 5; c++) {
        int p = t + 1024 * c;
        if (p < MM && kf[p]) lc++;
    }
    if (lc) atomicAdd(&s_cnt, lc);
    __syncthreads();
    int n_det = s_cnt;
    float thresh = -INFINITY;
    if (n_det > 100) {
        int lo = 0, hi = MM - 1;
        while (lo < hi) {
            int mid = (lo + hi) >> 1;
            __syncthreads();
            if (t == 0) s_cnt = 0;
            __syncthreads();
            int c2 = 0;
            for (int c = 0; c < 5; c++) {
                int p = t + 1024 * c;
                if (p < MM && p <= mid && kf[p]) c2++;
            }
            if (c2) atomicAdd(&s_cnt, c2);
            __syncthreads();
            if (s_cnt >= 100) hi = mid; else lo = mid + 1;
            __syncthreads();
        }
        thresh = scoresWS[base + lo];
    }
    float* ob = out;
    float* os = out + NB * MM * 4;
    float* oc = out + NB * MM * 5;
    float* ok = out + NB * MM * 6;
    for (int c = 0; c < 5; c++) {
        int p = t + 1024 * c;
        if (p < MM) {
            int g = base + p;
            float s = scoresWS[g];
            bool k = kf[p] && (s >= thresh) && (s >= 0.05f);
            float km = k ? 1.0f : 0.0f;
            float4 v = bx[c];
            ((float4*)ob)[g] = make_float4(v.x * km, v.y * km, v.z * km, v.w * km);
            os[g] = s * km;
            oc[g] = clsWS[g] * km;
            ok[g] = km;
        }
    }
}

extern "C" void kernel_launch(void* const* d_in, const int* in_sizes, int n_in,
                              void* d_out, int out_size, void* d_ws, size_t ws_size,
                              hipStream_t stream) {
    const float* cls = (const float*)d_in[0];
    const float* reg = (const float*)d_in[1];
    const float* ctr = (const float*)d_in[2];
    const float* locs = (const float*)d_in[3];
    (void)in_sizes; (void)n_in; (void)out_size;

    char* ws = (char*)d_ws;
    unsigned int* hist = (unsigned int*)(ws);                            // 10,485,760
    unsigned int* cnt = (unsigned int*)(ws + 10485760);                  // 512
    unsigned int* bcut = (unsigned int*)(ws + 10486272);                 // 512
    unsigned long long* compact = (unsigned long long*)(ws + 10486784);  // 2,621,440
    unsigned long long* pool = (unsigned long long*)(ws + 13108224);     // 640,000
    unsigned long long* sorted = (unsigned long long*)(ws + 13748224);   // 640,000
    float4* boxesWS = (float4*)(ws + 14388224);                          // 1,280,000
    float* scoresWS = (float*)(ws + 15668224);                           // 320,000
    float* clsWS = (float*)(ws + 15988224);                              // 320,000
    unsigned int* validWS = (unsigned int*)(ws + 16308224);              // 320,000
    unsigned long long* keepw = (unsigned long long*)(ws + 16628224);    // 10,240
    float* threshB = (float*)(ws + 16638464);                            // 256
    unsigned long long* mask = (unsigned long long*)(ws + 16638720);     // 51,445,760
    const size_t WS_NEED = 16638720ULL + 51445760ULL;                    // 68,084,480

    hipMemsetAsync(ws, 0, 10486784, stream);  // hist + cnt + bcut
    hipLaunchKernelGGL(k_hist, dim3(4096), dim3(256), 0, stream, cls, ctr, hist);
    hipLaunchKernelGGL(k_cutoff, dim3(80), dim3(256), 0, stream, hist, bcut);
    hipLaunchKernelGGL(k_compact, dim3(4096), dim3(256), 0, stream, cls, ctr, bcut, cnt, compact);
    hipLaunchKernelGGL(k_select, dim3(80), dim3(1024), 0, stream, cnt, compact, pool);
    hipLaunchKernelGGL(k_merge, dim3(NB), dim3(1024), 0, stream, pool, cnt, sorted);
    hipLaunchKernelGGL(k_decode, dim3((NB * MM + 255) / 256), dim3(256), 0, stream,
                       sorted, reg, locs, boxesWS, scoresWS, clsWS, validWS);
    if (ws_size >= WS_NEED) {
        hipLaunchKernelGGL(k_mask, dim3(NB * 110), dim3(256), 0, stream, boxesWS, mask);
        hipLaunchKernelGGL(k_scan, dim3(NB), dim3(64), 0, stream,
                           validWS, mask, scoresWS, keepw, threshB);
        hipLaunchKernelGGL(k_final, dim3((NB * MM + 511) / 512), dim3(512), 0, stream,
                           boxesWS, scoresWS, clsWS, keepw, threshB, (float*)d_out);
    } else {
        hipLaunchKernelGGL(k_nms, dim3(NB), dim3(1024), 0, stream,
                           boxesWS, scoresWS, clsWS, validWS, (float*)d_out);
    }
}

// Round 5
// 1344.933 us; speedup vs baseline: 5.0208x; 1.3134x over previous
//
#include <hip/hip_runtime.h>
#include <math.h>

#define NB 16
#define NLOC 21824
#define NCLS 80
#define NLVL 5
#define MM 5000
#define MROWS 5024      // MM padded for scan groups (314 groups of 16)
#define CAP 4096
#define EPB 1745920     // entries per batch = NLOC*NCLS

#define NSLOT 5
#define SLOTU64 1536    // 12288 B per slot (group = 10240 B + pad)

__device__ __forceinline__ int level_of(int r) {
    return (r < 1310720) ? 0 : (r < 1638400) ? 1 : (r < 1720320) ? 2 : (r < 1740800) ? 3 : 4;
}
__device__ __constant__ int d_estart[5] = {0, 1310720, 1638400, 1720320, 1740800};
__device__ __constant__ int d_lstart[5] = {0, 16384, 20480, 21504, 21760};
// k_mask block map: per-batch 110 blocks; start offset per row-chunk rc (cg_min = rc/2)
__device__ __constant__ int d_mstart[20] = {0,10,20,29,38,46,54,61,68,74,80,85,90,94,98,101,104,106,108,109};

// ---------------- Kernel A: per-(b,l) 15-bit histogram of candidate valbits ----------------
__global__ void k_hist(const float* __restrict__ cls, const float* __restrict__ ctr,
                       unsigned int* __restrict__ hist) {
    const long long total = (long long)NB * EPB;
    for (long long e = (long long)blockIdx.x * blockDim.x + threadIdx.x; e < total;
         e += (long long)gridDim.x * blockDim.x) {
        float x = cls[e];
        if (x <= -2.945f) continue;  // sigmoid(-2.945)=0.049968 < 0.05f, safe prescreen
        double sd = 1.0 / (1.0 + exp(-(double)x));
        float sf = (float)sd;
        if (!(sf > 0.05f)) continue;
        int b = (int)(e / EPB);
        int r = (int)(e - (long long)b * EPB);
        int l = level_of(r);
        int locg = r / 80;
        float c = ctr[(long long)b * NLOC + locg];
        double cd = 1.0 / (1.0 + exp(-(double)c));
        float val = sf * (float)cd;
        unsigned int vb = __float_as_uint(val);
        atomicAdd(&hist[(((long long)b * 5 + l) << 15) + (vb >> 15)], 1u);
    }
}

// ---------------- Kernel B: find cutoff bucket per (b,l) ----------------
__global__ void k_cutoff(const unsigned int* __restrict__ hist, unsigned int* __restrict__ bcut) {
    int g = blockIdx.x;  // 0..79
    const unsigned int* h = hist + ((long long)g << 15);
    __shared__ unsigned int ssum[256];
    int t = threadIdx.x;
    unsigned int s = 0;
    for (int i = 0; i < 128; i++) s += h[t * 128 + i];
    ssum[t] = s;
    __syncthreads();
    if (t == 0) {
        unsigned int cum = 0;
        int bucket = 0;
        int ch = 255;
        for (; ch >= 0; ch--) {
            if (cum + ssum[ch] >= 1000u) break;
            cum += ssum[ch];
        }
        if (ch >= 0) {
            int bi = ch * 128 + 127;
            for (; bi > ch * 128; bi--) {
                unsigned int c = h[bi];
                if (cum + c >= 1000u) break;
                cum += c;
            }
            bucket = bi;
        }
        bcut[g] = (unsigned int)bucket;
    }
}

// ---------------- Kernel C: compact candidates >= cutoff bucket ----------------
__global__ void k_compact(const float* __restrict__ cls, const float* __restrict__ ctr,
                          const unsigned int* __restrict__ bcut, unsigned int* __restrict__ cnt,
                          unsigned long long* __restrict__ compact) {
    const long long total = (long long)NB * EPB;
    for (long long e = (long long)blockIdx.x * blockDim.x + threadIdx.x; e < total;
         e += (long long)gridDim.x * blockDim.x) {
        float x = cls[e];
        if (x <= -2.945f) continue;
        double sd = 1.0 / (1.0 + exp(-(double)x));
        float sf = (float)sd;
        if (!(sf > 0.05f)) continue;
        int b = (int)(e / EPB);
        int r = (int)(e - (long long)b * EPB);
        int l = level_of(r);
        int locg = r / 80;
        float c = ctr[(long long)b * NLOC + locg];
        double cd = 1.0 / (1.0 + exp(-(double)c));
        float val = sf * (float)cd;
        unsigned int vb = __float_as_uint(val);
        int g = b * 5 + l;
        if ((vb >> 15) >= bcut[g]) {
            unsigned int pos = atomicAdd(&cnt[g], 1u);
            if (pos < CAP) {
                unsigned int idx = (unsigned int)(r - d_estart[l]);
                compact[(long long)g * CAP + pos] =
                    ((unsigned long long)vb << 21) | (unsigned long long)(0x1FFFFFu - idx);
            }
        }
    }
}

// ---------------- Kernel D: per-(b,l) bitonic sort + build global keys ----------------
__global__ void k_select(const unsigned int* __restrict__ cnt,
                         const unsigned long long* __restrict__ compact,
                         unsigned long long* __restrict__ pool) {
    __shared__ unsigned long long sk[CAP];
    int g = blockIdx.x;
    int b = g / 5, l = g % 5;
    int count = min((int)cnt[g], CAP);
    for (int p = threadIdx.x; p < CAP; p += blockDim.x)
        sk[p] = (p < count) ? compact[(long long)g * CAP + p] : 0ULL;
    __syncthreads();
    for (int k = 2; k <= CAP; k <<= 1) {
        for (int j = k >> 1; j > 0; j >>= 1) {
            for (int i = threadIdx.x; i < CAP; i += blockDim.x) {
                int ixj = i ^ j;
                if (ixj > i) {
                    unsigned long long a = sk[i], bb = sk[ixj];
                    bool desc = ((i & k) == 0);
                    if (desc ? (a < bb) : (a > bb)) { sk[i] = bb; sk[ixj] = a; }
                }
            }
            __syncthreads();
        }
    }
    int ksel = min(1000, count);
    for (int r = threadIdx.x; r < 1000; r += blockDim.x) {
        unsigned long long gk = 0ULL;
        if (r < ksel) {
            unsigned long long key = sk[r];
            unsigned int vb = (unsigned int)(key >> 21);
            unsigned int idx = 0x1FFFFFu - (unsigned int)(key & 0x1FFFFFu);
            float val = __uint_as_float(vb);
            float sc = sqrtf(val);
            unsigned long long sb = (unsigned long long)__float_as_uint(sc);
            gk = (sb << 34) | ((unsigned long long)(7 - l) << 31) |
                 ((unsigned long long)(1023 - r) << 21) | (unsigned long long)idx;
        }
        pool[(long long)b * MM + l * 1000 + r] = gk;
    }
}

// ---------------- Kernel E': 5-way merge by exact rank ----------------
__global__ __launch_bounds__(1024) void k_merge(const unsigned long long* __restrict__ pool,
                                                const unsigned int* __restrict__ cnt,
                                                unsigned long long* __restrict__ sorted) {
    __shared__ unsigned long long sp[MM];
    __shared__ int s_nz[5];
    int b = blockIdx.x, t = threadIdx.x;
    for (int p = t; p < MM; p += 1024) sp[p] = pool[(long long)b * MM + p];
    if (t < 5) s_nz[t] = (int)min(cnt[b * 5 + t], 1000u);
    __syncthreads();
    int nzTot = s_nz[0] + s_nz[1] + s_nz[2] + s_nz[3] + s_nz[4];
    for (int p = t; p < MM; p += 1024) {
        int l = p / 1000, r = p - l * 1000;
        unsigned long long K = sp[p];
        int rank;
        if (K) {
            rank = r;
#pragma unroll
            for (int l2 = 0; l2 < 5; ++l2) {
                if (l2 == l) continue;
                const unsigned long long* L = sp + l2 * 1000;
                int lo = 0, hi = s_nz[l2];
                while (lo < hi) {
                    int mid = (lo + hi) >> 1;
                    if (L[mid] > K) lo = mid + 1; else hi = mid;
                }
                rank += lo;
            }
        } else {
            int zi = 0;
#pragma unroll
            for (int l2 = 0; l2 < 5; ++l2) if (l2 < l) zi += 1000 - s_nz[l2];
            zi += r - s_nz[l];
            rank = nzTot + zi;
        }
        sorted[(long long)b * MM + rank] = K;
    }
}

// ---------------- Kernel F: decode boxes/scores/classes ----------------
__global__ void k_decode(const unsigned long long* __restrict__ sorted,
                         const float* __restrict__ reg, const float* __restrict__ locs,
                         float4* __restrict__ boxesWS, float* __restrict__ scoresWS,
                         float* __restrict__ clsWS, unsigned int* __restrict__ validWS) {
    int g = blockIdx.x * blockDim.x + threadIdx.x;
    if (g >= NB * MM) return;
    int b = g / MM;
    unsigned long long gk = sorted[g];
    float4 bx = make_float4(0.f, 0.f, 0.f, 0.f);
    float sc = 0.f, cf = 0.f;
    unsigned int v = 0;
    if (gk) {
        sc = __uint_as_float((unsigned int)(gk >> 34));
        int l = 7 - (int)((gk >> 31) & 7);
        int idx = (int)(gk & 0x1FFFFF);
        int loc = idx / 80;
        int c = idx - loc * 80;
        int gl = d_lstart[l] + loc;
        float lx = locs[gl * 2], ly = locs[gl * 2 + 1];
        const float* r4 = reg + ((long long)b * NLOC + gl) * 4;
        float x1 = fminf(fmaxf(lx - r4[0], 0.f), 1024.f);
        float y1 = fminf(fmaxf(ly - r4[1], 0.f), 1024.f);
        float x2 = fminf(fmaxf(lx + r4[2], 0.f), 1024.f);
        float y2 = fminf(fmaxf(ly + r4[3], 0.f), 1024.f);
        bx = make_float4(x1, y1, x2, y2);
        cf = (float)(c + 1);
        v = 1;
    }
    boxesWS[g] = bx;
    scoresWS[g] = sc;
    clsWS[g] = cf;
    validWS[g] = v;
}

// ---------------- Kernel M: pairwise suppression bitmask (tiled) ----------------
__global__ __launch_bounds__(256) void k_mask(const float4* __restrict__ boxesWS,
                                              unsigned long long* __restrict__ mask) {
    __shared__ float4 cb[512];
    __shared__ float ca[512];
    int id = blockIdx.x;
    int b = id / 110;
    int q = id - b * 110;
    int rc = 19;
    for (int r = 1; r < 20; ++r) if (q < d_mstart[r]) { rc = r - 1; break; }
    int cg = rc / 2 + (q - d_mstart[rc]);
    int t = threadIdx.x;
    int i = rc * 256 + t;
    int c0 = cg * 512;
    for (int c = t; c < 512; c += 256) {
        int j = c0 + c;
        float4 v = (j < MM) ? boxesWS[b * MM + j] : make_float4(0.f, 0.f, 0.f, 0.f);
        cb[c] = v;
        ca[c] = (v.z - v.x) * (v.w - v.y);
    }
    __syncthreads();
    if (i >= MM) return;
    float4 hb = boxesWS[b * MM + i];
    float hA = (hb.z - hb.x) * (hb.w - hb.y);
    int iw0 = i >> 6;
    int cg8 = cg * 8;
    unsigned long long wbuf[8];
#pragma unroll
    for (int k = 0; k < 8; ++k) {
        int w = cg8 + k;
        unsigned long long m = 0ULL;
        if (w >= iw0) {
            int cbase = w * 64 - c0;
            for (int jj = 0; jj < 64; ++jj) {
                float4 cbj = cb[cbase + jj];
                float xi1 = fmaxf(hb.x, cbj.x);
                float yi1 = fmaxf(hb.y, cbj.y);
                float xi2 = fminf(hb.z, cbj.z);
                float yi2 = fminf(hb.w, cbj.w);
                float inter = fmaxf(xi2 - xi1, 0.f) * fmaxf(yi2 - yi1, 0.f);
                float iou = inter / fmaxf(hA + ca[cbase + jj] - inter, 1e-9f);
                if (iou > 0.6f) m |= 1ULL << jj;
            }
            if (w == iw0) m &= (0xFFFFFFFFFFFFFFFEULL << (i & 63));  // keep only j > i
        }
        wbuf[k] = m;
    }
    unsigned long long* Mrow = mask + ((size_t)b * MROWS + (size_t)i) * 80 + cg8;
    if (iw0 <= cg8) {
        ((ulonglong2*)Mrow)[0] = make_ulonglong2(wbuf[0], wbuf[1]);
        ((ulonglong2*)Mrow)[1] = make_ulonglong2(wbuf[2], wbuf[3]);
        ((ulonglong2*)Mrow)[2] = make_ulonglong2(wbuf[4], wbuf[5]);
        ((ulonglong2*)Mrow)[3] = make_ulonglong2(wbuf[6], wbuf[7]);
    } else {
#pragma unroll
        for (int k = 0; k < 8; ++k)
            if (cg8 + k >= iw0) Mrow[k] = wbuf[k];
    }
}

// ---------------- Kernel S: pipelined bitmask scan ----------------
// 256 threads: all 4 waves stage group g+3 into a 5-slot LDS ring via
// global_load_lds(16B); counted s_waitcnt vmcnt(9) + raw s_barrier per group
// (3 loads/thread/iter, 3 groups in flight). Wave 0 consumes group g from LDS
// with the serial dcur chain. No big register buffers -> no spills.
__device__ __forceinline__ unsigned long long shfl_u64(unsigned long long v, int src) {
    int lo = __shfl((int)(unsigned int)v, src, 64);
    int hi = __shfl((int)(unsigned int)(v >> 32), src, 64);
    return ((unsigned long long)(unsigned int)hi << 32) | (unsigned int)lo;
}

__global__ __launch_bounds__(256, 1) void k_scan(const unsigned int* __restrict__ validWS,
                                                 const unsigned long long* __restrict__ mask,
                                                 const float* __restrict__ scoresWS,
                                                 unsigned long long* __restrict__ keepw,
                                                 float* __restrict__ threshB) {
    __shared__ unsigned long long slots[NSLOT * SLOTU64];  // 61440 B
    __shared__ unsigned long long kw[80];
    int b = blockIdx.x;
    int tid = threadIdx.x;
    int lane = tid & 63;
    const char* Mb = (const char*)mask + (size_t)b * ((size_t)MROWS * 80 * 8);

    // init removed-state (wave 0 registers)
    unsigned long long r0 = 0ULL, r1 = 0ULL;
    if (tid < 64) {
#pragma unroll 8
        for (int jj = 0; jj < 64; ++jj) {
            int j = lane * 64 + jj;
            unsigned int v = (j < MM) ? validWS[b * MM + j] : 0u;
            r0 |= (unsigned long long)(v ? 0u : 1u) << jj;
        }
        if (lane < 16) {
#pragma unroll 8
            for (int jj = 0; jj < 64; ++jj) {
                int j = (lane + 64) * 64 + jj;
                unsigned int v = (j < MM) ? validWS[b * MM + j] : 0u;
                r1 |= (unsigned long long)(v ? 0u : 1u) << jj;
            }
        }
    }

    // stage group g (10240B, padded to 12288B read) into ring slot s
    auto stage = [&](int g, int s) {
        const char* src = Mb + (size_t)g * 10240 + (size_t)tid * 16;
        unsigned long long* dst = &slots[s * SLOTU64 + (tid >> 6) * 128];
        __builtin_amdgcn_global_load_lds(
            (const __attribute__((address_space(1))) void*)src,
            (__attribute__((address_space(3))) void*)dst, 16, 0, 0);
        __builtin_amdgcn_global_load_lds(
            (const __attribute__((address_space(1))) void*)(src + 4096),
            (__attribute__((address_space(3))) void*)(dst + 512), 16, 0, 0);
        __builtin_amdgcn_global_load_lds(
            (const __attribute__((address_space(1))) void*)(src + 8192),
            (__attribute__((address_space(3))) void*)(dst + 1024), 16, 0, 0);
    };

    stage(0, 0);
    stage(1, 1);
    stage(2, 2);

    unsigned long long dcur = 0ULL, gmask0 = 0ULL, gmask1 = 0ULL;
    for (int g = 0; g < 314; ++g) {
        int g3 = (g + 3 < 314) ? g + 3 : 313;          // tail: reload 313 (uniform vmcnt count)
        stage(g3, (g + 3) % NSLOT);
        asm volatile("s_waitcnt vmcnt(9)" ::: "memory");  // group g landed (all waves do this)
        __builtin_amdgcn_s_barrier();
        __builtin_amdgcn_sched_barrier(0);
        if (tid < 64) {
            const unsigned long long* sk = &slots[(g % NSLOT) * SLOTU64];
            int iw = g >> 2;
            if ((g & 3) == 0) {  // RESYNC: refresh replicated diagonal word + gate masks
                unsigned long long src_ = (iw < 64) ? r0 : r1;
                dcur = shfl_u64(src_, iw & 63);
                gmask0 = (lane >= iw) ? ~0ULL : 0ULL;
                gmask1 = (lane < 16 && (lane + 64) >= iw) ? ~0ULL : 0ULL;
            }
            unsigned long long X0v[16], X1v[16], XDv[16];
#pragma unroll
            for (int k = 0; k < 16; ++k) {
                X0v[k] = sk[k * 80 + lane];
                X1v[k] = (lane < 16) ? sk[k * 80 + 64 + lane] : 0ULL;
                XDv[k] = sk[k * 80 + iw];  // uniform addr -> broadcast
            }
            int base_ = (g * 16) & 63;
#pragma unroll
            for (int k = 0; k < 16; ++k) {
                int sh_ = (base_ + k) & 63;
                unsigned long long m_ = (((dcur >> sh_) & 1ULL) == 0ULL) ? ~0ULL : 0ULL;
                dcur |= XDv[k] & m_;
                r0 |= X0v[k] & m_ & gmask0;
                r1 |= X1v[k] & m_ & gmask1;
            }
        }
    }

    // post-select
    if (tid < 64) {
        unsigned long long k0 = ~r0;
        kw[lane] = k0;
        keepw[b * 80 + lane] = k0;
        if (lane < 16) {
            unsigned long long k1 = ~r1;
            kw[64 + lane] = k1;
            keepw[b * 80 + 64 + lane] = k1;
        }
    }
    __syncthreads();
    if (tid == 0) {
        int ndet = 0;
        for (int w = 0; w < 80; ++w) ndet += __popcll(kw[w]);
        float th = -INFINITY;
        if (ndet > 100) {
            int cum = 0, pos = -1;
            for (int w = 0; w < 80 && pos < 0; ++w) {
                int c = __popcll(kw[w]);
                if (cum + c >= 100) {
                    unsigned long long word = kw[w];
                    for (int bb = 0; bb < 64; ++bb) {
                        cum += (int)((word >> bb) & 1ULL);
                        if (cum == 100) { pos = w * 64 + bb; break; }
                    }
                } else {
                    cum += c;
                }
            }
            th = scoresWS[b * MM + pos];
        }
        threshB[b] = th;
    }
}

// ---------------- Kernel Z: masked output write ----------------
__global__ void k_final(const float4* __restrict__ boxesWS, const float* __restrict__ scoresWS,
                        const float* __restrict__ clsWS, const unsigned long long* __restrict__ keepw,
                        const float* __restrict__ threshB, float* __restrict__ out) {
    int g = blockIdx.x * blockDim.x + threadIdx.x;
    if (g >= NB * MM) return;
    int b = g / MM;
    int p = g - b * MM;
    bool kb = (keepw[b * 80 + (p >> 6)] >> (p & 63)) & 1ULL;
    float s = scoresWS[g];
    float th = threshB[b];
    bool k = kb && (s >= th) && (s >= 0.05f);
    float km = k ? 1.0f : 0.0f;
    float4 v = boxesWS[g];
    float* ob = out;
    float* os = out + NB * MM * 4;
    float* oc = out + NB * MM * 5;
    float* ok = out + NB * MM * 6;
    ((float4*)ob)[g] = make_float4(v.x * km, v.y * km, v.z * km, v.w * km);
    os[g] = s * km;
    oc[g] = clsWS[g] * km;
    ok[g] = km;
}

// ---------------- Fallback: sequential NMS (used only if ws too small) ----------------
__global__ __launch_bounds__(1024) void k_nms(const float4* __restrict__ boxesWS,
                                              const float* __restrict__ scoresWS,
                                              const float* __restrict__ clsWS,
                                              const unsigned int* __restrict__ validWS,
                                              float* __restrict__ out) {
    int b = blockIdx.x;
    int t = threadIdx.x;
    __shared__ unsigned char kf[MM];
    __shared__ int s_min;
    __shared__ int s_cnt;
    float4 bx[5];
    float ar[5];
    int base = b * MM;
    for (int c = 0; c < 5; c++) {
        int p = t + 1024 * c;
        bx[c] = make_float4(0.f, 0.f, 0.f, 0.f);
        ar[c] = 0.f;
        if (p < MM) {
            kf[p] = (unsigned char)validWS[base + p];
            float4 v = boxesWS[base + p];
            bx[c] = v;
            ar[c] = (v.z - v.x) * (v.w - v.y);
        }
    }
    __syncthreads();
    int i = -1;
    while (true) {
        int nh = -1;
        int wstart = i + 1;
        while (wstart < MM) {
            if (t == 0) s_min = 0x7FFFFFFF;
            __syncthreads();
            int p = wstart + t;
            if (p < MM && kf[p]) atomicMin(&s_min, p);
            __syncthreads();
            int sm = s_min;
            __syncthreads();
            if (sm != 0x7FFFFFFF) { nh = sm; break; }
            wstart += 1024;
        }
        if (nh < 0) break;
        i = nh;
        float4 hb = boxesWS[base + i];
        float ha = (hb.z - hb.x) * (hb.w - hb.y);
        for (int c = 0; c < 5; c++) {
            int p = t + 1024 * c;
            if (p > i && p < MM && kf[p]) {
                float xi1 = fmaxf(hb.x, bx[c].x);
                float yi1 = fmaxf(hb.y, bx[c].y);
                float xi2 = fminf(hb.z, bx[c].z);
                float yi2 = fminf(hb.w, bx[c].w);
                float inter = fmaxf(xi2 - xi1, 0.f) * fmaxf(yi2 - yi1, 0.f);
                float iou = inter / fmaxf(ha + ar[c] - inter, 1e-9f);
                if (iou > 0.6f) kf[p] = 0;
            }
        }
        __syncthreads();
    }
    if (t == 0) s_cnt = 0;
    __syncthreads();
    int lc = 0;
    for (int c = 0; c < 5; c++) {
        int p = t + 1024 * c;
        if (p < MM && kf[p]) lc++;
    }
    if (lc) atomicAdd(&s_cnt, lc);
    __syncthreads();
    int n_det = s_cnt;
    float thresh = -INFINITY;
    if (n_det > 100) {
        int lo = 0, hi = MM - 1;
        while (lo < hi) {
            int mid = (lo + hi) >> 1;
            __syncthreads();
            if (t == 0) s_cnt = 0;
            __syncthreads();
            int c2 = 0;
            for (int c = 0; c < 5; c++) {
                int p = t + 1024 * c;
                if (p < MM && p <= mid && kf[p]) c2++;
            }
            if (c2) atomicAdd(&s_cnt, c2);
            __syncthreads();
            if (s_cnt >= 100) hi = mid; else lo = mid + 1;
            __syncthreads();
        }
        thresh = scoresWS[base + lo];
    }
    float* ob = out;
    float* os = out + NB * MM * 4;
    float* oc = out + NB * MM * 5;
    float* ok = out + NB * MM * 6;
    for (int c = 0; c < 5; c++) {
        int p = t + 1024 * c;
        if (p < MM) {
            int g = base + p;
            float s = scoresWS[g];
            bool k = kf[p] && (s >= thresh) && (s >= 0.05f);
            float km = k ? 1.0f : 0.0f;
            float4 v = bx[c];
            ((float4*)ob)[g] = make_float4(v.x * km, v.y * km, v.z * km, v.w * km);
            os[g] = s * km;
            oc[g] = clsWS[g] * km;
            ok[g] = km;
        }
    }
}

extern "C" void kernel_launch(void* const* d_in, const int* in_sizes, int n_in,
                              void* d_out, int out_size, void* d_ws, size_t ws_size,
                              hipStream_t stream) {
    const float* cls = (const float*)d_in[0];
    const float* reg = (const float*)d_in[1];
    const float* ctr = (const float*)d_in[2];
    const float* locs = (const float*)d_in[3];
    (void)in_sizes; (void)n_in; (void)out_size;

    char* ws = (char*)d_ws;
    unsigned int* hist = (unsigned int*)(ws);                            // 10,485,760
    unsigned int* cnt = (unsigned int*)(ws + 10485760);                  // 512
    unsigned int* bcut = (unsigned int*)(ws + 10486272);                 // 512
    unsigned long long* compact = (unsigned long long*)(ws + 10486784);  // 2,621,440
    unsigned long long* pool = (unsigned long long*)(ws + 13108224);     // 640,000
    unsigned long long* sorted = (unsigned long long*)(ws + 13748224);   // 640,000
    float4* boxesWS = (float4*)(ws + 14388224);                          // 1,280,000
    float* scoresWS = (float*)(ws + 15668224);                           // 320,000
    float* clsWS = (float*)(ws + 15988224);                              // 320,000
    unsigned int* validWS = (unsigned int*)(ws + 16308224);              // 320,000
    unsigned long long* keepw = (unsigned long long*)(ws + 16628224);    // 10,240
    float* threshB = (float*)(ws + 16638464);                            // 256
    unsigned long long* mask = (unsigned long long*)(ws + 16638720);     // 51,445,760
    // + 4096 B slack: k_scan stages fixed 12288 B/group (2048 B over-read on last group)
    const size_t WS_NEED = 16638720ULL + 51445760ULL + 4096ULL;          // 68,088,576

    hipMemsetAsync(ws, 0, 10486784, stream);  // hist + cnt + bcut
    hipLaunchKernelGGL(k_hist, dim3(4096), dim3(256), 0, stream, cls, ctr, hist);
    hipLaunchKernelGGL(k_cutoff, dim3(80), dim3(256), 0, stream, hist, bcut);
    hipLaunchKernelGGL(k_compact, dim3(4096), dim3(256), 0, stream, cls, ctr, bcut, cnt, compact);
    hipLaunchKernelGGL(k_select, dim3(80), dim3(1024), 0, stream, cnt, compact, pool);
    hipLaunchKernelGGL(k_merge, dim3(NB), dim3(1024), 0, stream, pool, cnt, sorted);
    hipLaunchKernelGGL(k_decode, dim3((NB * MM + 255) / 256), dim3(256), 0, stream,
                       sorted, reg, locs, boxesWS, scoresWS, clsWS, validWS);
    if (ws_size >= WS_NEED) {
        hipLaunchKernelGGL(k_mask, dim3(NB * 110), dim3(256), 0, stream, boxesWS, mask);
        hipLaunchKernelGGL(k_scan, dim3(NB), dim3(256), 0, stream,
                           validWS, mask, scoresWS, keepw, threshB);
        hipLaunchKernelGGL(k_final, dim3((NB * MM + 511) / 512), dim3(512), 0, stream,
                           boxesWS, scoresWS, clsWS, keepw, threshB, (float*)d_out);
    } else {
        hipLaunchKernelGGL(k_nms, dim3(NB), dim3(1024), 0, stream,
                           boxesWS, scoresWS, clsWS, validWS, (float*)d_out);
    }
}